// Round 1
// baseline (558.215 us; speedup 1.0000x reference)
//
#include <hip/hip_runtime.h>
#include <hip/hip_bf16.h>

// Problem constants (fixed by the reference)
#define NPTS 50000   // N data points
#define DIM  256     // feature dim (K of the GEMM)
#define BQ   2048    // batch of queries (M of the GEMM)

#define TILE 128     // 128x128 output tile per block
#define BK   32      // K-slice per MFMA step
#define NCHUNKS 391  // ceil(50000/128)

// ws layout in floats:
//  [0,      2048)  : accOut   (fp32 accumulator per query row, atomicAdd target)
//  [2048,   4096)  : x2       (||x_b||^2)
//  [4096,  54096)  : s2       (||s_n||^2)
//  [54096,104096)  : w        (labels * relu(lambdas))
#define WS_ACC 0
#define WS_X2  2048
#define WS_S2  4096
#define WS_W   54096

typedef __bf16 bf16x8 __attribute__((ext_vector_type(8)));
typedef __bf16 bf16x4 __attribute__((ext_vector_type(4)));
typedef float  f32x4  __attribute__((ext_vector_type(4)));

// One wave per row: compute row squared-norms for data_set (-> s2, w) and x (-> x2).
__global__ __launch_bounds__(256) void svm_precompute(
    const float* __restrict__ x, const float* __restrict__ s,
    const float* __restrict__ labels, const float* __restrict__ lambdas,
    float* __restrict__ ws) {
  int wid  = blockIdx.x * 4 + (threadIdx.x >> 6);
  int lane = threadIdx.x & 63;
  const float* src;
  if (wid < NPTS)           src = s + (size_t)wid * DIM;
  else if (wid < NPTS + BQ) src = x + (size_t)(wid - NPTS) * DIM;
  else return;
  float4 v = reinterpret_cast<const float4*>(src)[lane];  // 64 lanes * 4 = 256
  float ss = v.x * v.x + v.y * v.y + v.z * v.z + v.w * v.w;
  #pragma unroll
  for (int off = 32; off > 0; off >>= 1) ss += __shfl_xor(ss, off);
  if (lane == 0) {
    if (wid < NPTS) {
      ws[WS_S2 + wid] = ss;
      float lam = lambdas[wid];
      ws[WS_W + wid] = labels[wid] * (lam > 0.0f ? lam : 0.0f);
    } else {
      ws[WS_X2 + (wid - NPTS)] = ss;
    }
  }
}

// Main fused kernel: 128x128 tile of cross = x . s^T via bf16 MFMA,
// then exp(c - (x2+s2)/2) * w, reduced over n, atomicAdd into accOut.
__global__ __launch_bounds__(256) void svm_main(
    const float* __restrict__ x, const float* __restrict__ s,
    const float* __restrict__ ws) {
  __shared__ __bf16 sA[TILE * BK];
  __shared__ __bf16 sB[TILE * BK];

  const int t    = threadIdx.x;
  const int wave = t >> 6;
  const int lane = t & 63;
  const int quad = lane >> 4;
  const int l16  = lane & 15;
  const int wm   = (wave & 1) * 64;   // wave's m-offset within tile
  const int wn   = (wave >> 1) * 64;  // wave's n-offset within tile
  const int bRow0 = blockIdx.y * TILE;
  const int n0    = blockIdx.x * TILE;

  f32x4 acc[4][4];
  #pragma unroll
  for (int i = 0; i < 4; ++i)
    #pragma unroll
    for (int j = 0; j < 4; ++j)
      acc[i][j] = (f32x4)(0.0f);

  for (int kt = 0; kt < DIM / BK; ++kt) {
    const int k0 = kt * BK;
    __syncthreads();  // protect prior iteration's LDS reads
    // Stage A (x) and B (data_set) k-slices, converting fp32 -> bf16.
    // 1024 float4 slots per tile; 256 threads x 4.
    #pragma unroll
    for (int i = 0; i < 4; ++i) {
      int slot = t + i * 256;
      int r  = slot >> 3;     // tile row 0..127
      int c4 = slot & 7;      // float4 index within 32-wide k-slice
      float4 va = reinterpret_cast<const float4*>(
          x + (size_t)(bRow0 + r) * DIM + k0)[c4];
      bf16x4 ha = { (__bf16)va.x, (__bf16)va.y, (__bf16)va.z, (__bf16)va.w };
      *reinterpret_cast<bf16x4*>(&sA[r * BK + c4 * 4]) = ha;

      int nrow = n0 + r;
      float4 vb = make_float4(0.f, 0.f, 0.f, 0.f);
      if (nrow < NPTS)
        vb = reinterpret_cast<const float4*>(
            s + (size_t)nrow * DIM + k0)[c4];
      bf16x4 hb = { (__bf16)vb.x, (__bf16)vb.y, (__bf16)vb.z, (__bf16)vb.w };
      *reinterpret_cast<bf16x4*>(&sB[r * BK + c4 * 4]) = hb;
    }
    __syncthreads();

    // LDS -> fragments (ds_read_b128), then 16 MFMAs.
    bf16x8 af[4], bfv[4];
    #pragma unroll
    for (int mi = 0; mi < 4; ++mi)
      af[mi] = *reinterpret_cast<const bf16x8*>(
          &sA[(wm + mi * 16 + l16) * BK + quad * 8]);
    #pragma unroll
    for (int ni = 0; ni < 4; ++ni)
      bfv[ni] = *reinterpret_cast<const bf16x8*>(
          &sB[(wn + ni * 16 + l16) * BK + quad * 8]);
    #pragma unroll
    for (int mi = 0; mi < 4; ++mi)
      #pragma unroll
      for (int ni = 0; ni < 4; ++ni)
        acc[mi][ni] = __builtin_amdgcn_mfma_f32_16x16x32_bf16(
            af[mi], bfv[ni], acc[mi][ni], 0, 0, 0);
  }

  // Epilogue. C/D layout (verified, guide §3): col = lane&15 (n-dim),
  // row = quad*4 + reg (m-dim).
  const float* x2g = ws + WS_X2;
  const float* s2g = ws + WS_S2;
  const float* wg  = ws + WS_W;
  float* accOut    = (float*)ws + WS_ACC;

  float s2v[4], wv[4];
  #pragma unroll
  for (int ni = 0; ni < 4; ++ni) {
    int n = n0 + wn + ni * 16 + l16;
    bool ok = n < NPTS;
    s2v[ni] = ok ? s2g[n] : 0.0f;
    wv[ni]  = ok ? wg[n]  : 0.0f;
  }
  #pragma unroll
  for (int mi = 0; mi < 4; ++mi) {
    const int mbase = wm + mi * 16 + quad * 4;  // local row base
    #pragma unroll
    for (int reg = 0; reg < 4; ++reg) {
      float x2r = x2g[bRow0 + mbase + reg];
      float ps = 0.0f;
      #pragma unroll
      for (int ni = 0; ni < 4; ++ni) {
        float c = acc[mi][ni][reg];
        // exp(c - (x2+s2)/2); arg ~ -128 -> underflows to 0, never NaN/inf
        ps += __expf(__builtin_fmaf(-0.5f, x2r + s2v[ni], c)) * wv[ni];
      }
      // reduce across the 16 lanes holding the 16 n-columns of this row
      ps += __shfl_xor(ps, 1);
      ps += __shfl_xor(ps, 2);
      ps += __shfl_xor(ps, 4);
      ps += __shfl_xor(ps, 8);
      if (l16 == 0) atomicAdd(&accOut[bRow0 + mbase + reg], ps);
    }
  }
}

__global__ __launch_bounds__(256) void svm_finalize(
    const float* __restrict__ ws, const float* __restrict__ bias,
    float* __restrict__ out) {
  int i = blockIdx.x * 256 + threadIdx.x;
  if (i < BQ) out[i] = tanhf(ws[WS_ACC + i] + bias[0]);
}

extern "C" void kernel_launch(void* const* d_in, const int* in_sizes, int n_in,
                              void* d_out, int out_size, void* d_ws, size_t ws_size,
                              hipStream_t stream) {
  const float* x       = (const float*)d_in[0];  // [2048, 256]
  const float* s       = (const float*)d_in[1];  // [50000, 256]
  const float* labels  = (const float*)d_in[2];  // [50000]
  const float* lambdas = (const float*)d_in[3];  // [50000]
  const float* bias    = (const float*)d_in[4];  // [1]
  float* out = (float*)d_out;                    // [2048]
  float* ws  = (float*)d_ws;

  // zero the fp32 accumulator region (ws is poisoned 0xAA before every launch)
  hipMemsetAsync(ws, 0, BQ * sizeof(float), stream);

  // (N + B) row-norm waves, 4 waves per block
  svm_precompute<<<(NPTS + BQ + 3) / 4, 256, 0, stream>>>(x, s, labels, lambdas, ws);

  dim3 grid(NCHUNKS, BQ / TILE);  // 391 x 16
  svm_main<<<grid, 256, 0, stream>>>(x, s, ws);

  svm_finalize<<<BQ / 256, 256, 0, stream>>>(ws, bias, out);
}

// Round 2
// 252.147 us; speedup vs baseline: 2.2139x; 2.2139x over previous
//
#include <hip/hip_runtime.h>
#include <hip/hip_bf16.h>

// Problem constants (fixed by the reference)
#define NPTS 50000   // N data points
#define DIM  256     // feature dim (K of the GEMM)
#define BQ   2048    // batch of queries (M of the GEMM)
#define NPAD 50048   // N padded to multiple of 128

#define TILE 128     // 128x128 output tile per block
#define BK   32      // K-slice per MFMA step
#define NCHUNKS 391  // NPAD/128

// ---------- fast-path ws layout (float offsets) ----------
#define WS_ACC 0
#define WS_X2  2048
#define WS_S2  4096
#define WS_W   54144
#define WS_XB  104192
#define WS_SB  366336
#define WS_TOTAL_BYTES (6772480ull * 4ull)  // 27,089,920 B

// ---------- v1 fallback ws layout ----------
#define V1_ACC 0
#define V1_X2  2048
#define V1_S2  4096
#define V1_W   54096

typedef __bf16 bf16x8 __attribute__((ext_vector_type(8)));
typedef __bf16 bf16x4 __attribute__((ext_vector_type(4)));
typedef float  f32x4  __attribute__((ext_vector_type(4)));
typedef unsigned int u32;

__device__ __forceinline__ void async_copy16(const __bf16* g, __bf16* l) {
  __builtin_amdgcn_global_load_lds(
      (const __attribute__((address_space(1))) u32*)g,
      (__attribute__((address_space(3))) u32*)l, 16, 0, 0);
}

// ============================================================
// FAST PATH
// ============================================================

// One wave per row: fp32->bf16 convert into ws, plus norms and w.
__global__ __launch_bounds__(256) void svm_precvt(
    const float* __restrict__ x, const float* __restrict__ s,
    const float* __restrict__ labels, const float* __restrict__ lambdas,
    float* __restrict__ ws) {
  int wid  = blockIdx.x * 4 + (threadIdx.x >> 6);
  int lane = threadIdx.x & 63;
  __bf16* xb = (__bf16*)(ws + WS_XB);
  __bf16* sb = (__bf16*)(ws + WS_SB);

  if (wid < NPAD) {
    float4 v = make_float4(0.f, 0.f, 0.f, 0.f);
    if (wid < NPTS)
      v = reinterpret_cast<const float4*>(s + (size_t)wid * DIM)[lane];
    bf16x4 h = { (__bf16)v.x, (__bf16)v.y, (__bf16)v.z, (__bf16)v.w };
    *reinterpret_cast<bf16x4*>(sb + (size_t)wid * DIM + lane * 4) = h;
    float ss = v.x * v.x + v.y * v.y + v.z * v.z + v.w * v.w;
    #pragma unroll
    for (int off = 32; off > 0; off >>= 1) ss += __shfl_xor(ss, off);
    if (lane == 0) {
      ws[WS_S2 + wid] = ss;
      float lam = (wid < NPTS) ? lambdas[wid] : 0.0f;
      float lab = (wid < NPTS) ? labels[wid] : 0.0f;
      ws[WS_W + wid] = lab * (lam > 0.0f ? lam : 0.0f);
    }
  } else if (wid < NPAD + BQ) {
    int r = wid - NPAD;
    float4 v = reinterpret_cast<const float4*>(x + (size_t)r * DIM)[lane];
    bf16x4 h = { (__bf16)v.x, (__bf16)v.y, (__bf16)v.z, (__bf16)v.w };
    *reinterpret_cast<bf16x4*>(xb + (size_t)r * DIM + lane * 4) = h;
    float ss = v.x * v.x + v.y * v.y + v.z * v.z + v.w * v.w;
    #pragma unroll
    for (int off = 32; off > 0; off >>= 1) ss += __shfl_xor(ss, off);
    if (lane == 0) ws[WS_X2 + r] = ss;
  }
}

// m97-style GEMM + fused RBF epilogue. All-bf16 inputs in ws, no bounds checks.
__global__ __launch_bounds__(256) void svm_main2(float* __restrict__ ws) {
  __shared__ __bf16 sA[TILE * BK];  // 8 KB, unpadded (global_load_lds layout)
  __shared__ __bf16 sB[TILE * BK];

  const __bf16* xb = (const __bf16*)(ws + WS_XB);
  const __bf16* sb = (const __bf16*)(ws + WS_SB);

  const int t    = threadIdx.x;
  const int wave = t >> 6;
  const int lane = t & 63;
  const int quad = lane >> 4;
  const int l16  = lane & 15;
  const int wm   = (wave & 1) * 64;
  const int wn   = (wave >> 1) * 64;

  // swizzle: m-chunk fast-varying -> 16 consecutive blocks share one B tile
  const int bid    = blockIdx.x;
  const int bRow0  = (bid & 15) * TILE;
  const int n0     = (bid >> 4) * TILE;

  // staging coords: wave covers tile rows [wave*32, wave*32+32), issue j adds 16
  const int srow   = wave * 32 + (lane >> 2);
  const int schunk = (lane & 3) * 8;  // bf16 elems (16 B chunk within 64 B row)
  const __bf16* gA = xb + (size_t)(bRow0 + srow) * DIM + schunk;
  const __bf16* gB = sb + (size_t)(n0 + srow) * DIM + schunk;
  __bf16* lA = &sA[(wave * 32) * BK + lane * 8];
  __bf16* lB = &sB[(wave * 32) * BK + lane * 8];

  f32x4 acc[4][4];
  #pragma unroll
  for (int i = 0; i < 4; ++i)
    #pragma unroll
    for (int j = 0; j < 4; ++j)
      acc[i][j] = (f32x4)(0.0f);

  for (int kt = 0; kt < DIM / BK; ++kt) {
    __syncthreads();  // prior iteration's LDS reads complete
    #pragma unroll
    for (int j = 0; j < 2; ++j) {
      async_copy16(gA + (size_t)j * 16 * DIM + kt * BK, lA + j * 16 * BK);
      async_copy16(gB + (size_t)j * 16 * DIM + kt * BK, lB + j * 16 * BK);
    }
    __syncthreads();  // vmcnt(0) drained by compiler before barrier

    bf16x8 af[4], bfv[4];
    #pragma unroll
    for (int mi = 0; mi < 4; ++mi)
      af[mi] = *reinterpret_cast<const bf16x8*>(
          &sA[(wm + mi * 16 + l16) * BK + quad * 8]);
    #pragma unroll
    for (int ni = 0; ni < 4; ++ni)
      bfv[ni] = *reinterpret_cast<const bf16x8*>(
          &sB[(wn + ni * 16 + l16) * BK + quad * 8]);
    #pragma unroll
    for (int mi = 0; mi < 4; ++mi)
      #pragma unroll
      for (int ni = 0; ni < 4; ++ni)
        acc[mi][ni] = __builtin_amdgcn_mfma_f32_16x16x32_bf16(
            af[mi], bfv[ni], acc[mi][ni], 0, 0, 0);
  }

  // Epilogue: exp(c - (x2+s2)/2) * w, reduce over n-cols, atomicAdd per row.
  // C/D layout: col = lane&15 (n), row = quad*4 + reg (m).
  const float* x2g = ws + WS_X2;
  const float* s2g = ws + WS_S2;
  const float* wg  = ws + WS_W;
  float* accOut    = ws + WS_ACC;

  float s2v[4], wv[4];
  #pragma unroll
  for (int ni = 0; ni < 4; ++ni) {
    int n = n0 + wn + ni * 16 + l16;
    s2v[ni] = s2g[n];
    wv[ni]  = wg[n];
  }
  #pragma unroll
  for (int mi = 0; mi < 4; ++mi) {
    const int mbase = wm + mi * 16 + quad * 4;
    #pragma unroll
    for (int reg = 0; reg < 4; ++reg) {
      float x2r = x2g[bRow0 + mbase + reg];
      float ps = 0.0f;
      #pragma unroll
      for (int ni = 0; ni < 4; ++ni) {
        float c = acc[mi][ni][reg];
        ps += __expf(__builtin_fmaf(-0.5f, x2r + s2v[ni], c)) * wv[ni];
      }
      ps += __shfl_xor(ps, 1);
      ps += __shfl_xor(ps, 2);
      ps += __shfl_xor(ps, 4);
      ps += __shfl_xor(ps, 8);
      if (l16 == 0) atomicAdd(&accOut[bRow0 + mbase + reg], ps);
    }
  }
}

// ============================================================
// V1 FALLBACK (round-1 kernels, used only if ws_size too small)
// ============================================================

__global__ __launch_bounds__(256) void svm_precompute(
    const float* __restrict__ x, const float* __restrict__ s,
    const float* __restrict__ labels, const float* __restrict__ lambdas,
    float* __restrict__ ws) {
  int wid  = blockIdx.x * 4 + (threadIdx.x >> 6);
  int lane = threadIdx.x & 63;
  const float* src;
  if (wid < NPTS)           src = s + (size_t)wid * DIM;
  else if (wid < NPTS + BQ) src = x + (size_t)(wid - NPTS) * DIM;
  else return;
  float4 v = reinterpret_cast<const float4*>(src)[lane];
  float ss = v.x * v.x + v.y * v.y + v.z * v.z + v.w * v.w;
  #pragma unroll
  for (int off = 32; off > 0; off >>= 1) ss += __shfl_xor(ss, off);
  if (lane == 0) {
    if (wid < NPTS) {
      ws[V1_S2 + wid] = ss;
      float lam = lambdas[wid];
      ws[V1_W + wid] = labels[wid] * (lam > 0.0f ? lam : 0.0f);
    } else {
      ws[V1_X2 + (wid - NPTS)] = ss;
    }
  }
}

__global__ __launch_bounds__(256) void svm_main(
    const float* __restrict__ x, const float* __restrict__ s,
    const float* __restrict__ ws) {
  __shared__ __bf16 sA[TILE * BK];
  __shared__ __bf16 sB[TILE * BK];

  const int t    = threadIdx.x;
  const int wave = t >> 6;
  const int lane = t & 63;
  const int quad = lane >> 4;
  const int l16  = lane & 15;
  const int wm   = (wave & 1) * 64;
  const int wn   = (wave >> 1) * 64;
  const int bRow0 = blockIdx.y * TILE;
  const int n0    = blockIdx.x * TILE;

  f32x4 acc[4][4];
  #pragma unroll
  for (int i = 0; i < 4; ++i)
    #pragma unroll
    for (int j = 0; j < 4; ++j)
      acc[i][j] = (f32x4)(0.0f);

  for (int kt = 0; kt < DIM / BK; ++kt) {
    const int k0 = kt * BK;
    __syncthreads();
    #pragma unroll
    for (int i = 0; i < 4; ++i) {
      int slot = t + i * 256;
      int r  = slot >> 3;
      int c4 = slot & 7;
      float4 va = reinterpret_cast<const float4*>(
          x + (size_t)(bRow0 + r) * DIM + k0)[c4];
      bf16x4 ha = { (__bf16)va.x, (__bf16)va.y, (__bf16)va.z, (__bf16)va.w };
      *reinterpret_cast<bf16x4*>(&sA[r * BK + c4 * 4]) = ha;

      int nrow = n0 + r;
      float4 vb = make_float4(0.f, 0.f, 0.f, 0.f);
      if (nrow < NPTS)
        vb = reinterpret_cast<const float4*>(
            s + (size_t)nrow * DIM + k0)[c4];
      bf16x4 hb = { (__bf16)vb.x, (__bf16)vb.y, (__bf16)vb.z, (__bf16)vb.w };
      *reinterpret_cast<bf16x4*>(&sB[r * BK + c4 * 4]) = hb;
    }
    __syncthreads();

    bf16x8 af[4], bfv[4];
    #pragma unroll
    for (int mi = 0; mi < 4; ++mi)
      af[mi] = *reinterpret_cast<const bf16x8*>(
          &sA[(wm + mi * 16 + l16) * BK + quad * 8]);
    #pragma unroll
    for (int ni = 0; ni < 4; ++ni)
      bfv[ni] = *reinterpret_cast<const bf16x8*>(
          &sB[(wn + ni * 16 + l16) * BK + quad * 8]);
    #pragma unroll
    for (int mi = 0; mi < 4; ++mi)
      #pragma unroll
      for (int ni = 0; ni < 4; ++ni)
        acc[mi][ni] = __builtin_amdgcn_mfma_f32_16x16x32_bf16(
            af[mi], bfv[ni], acc[mi][ni], 0, 0, 0);
  }

  const float* x2g = ws + V1_X2;
  const float* s2g = ws + V1_S2;
  const float* wg  = ws + V1_W;
  float* accOut    = (float*)ws + V1_ACC;

  float s2v[4], wv[4];
  #pragma unroll
  for (int ni = 0; ni < 4; ++ni) {
    int n = n0 + wn + ni * 16 + l16;
    bool ok = n < NPTS;
    s2v[ni] = ok ? s2g[n] : 0.0f;
    wv[ni]  = ok ? wg[n]  : 0.0f;
  }
  #pragma unroll
  for (int mi = 0; mi < 4; ++mi) {
    const int mbase = wm + mi * 16 + quad * 4;
    #pragma unroll
    for (int reg = 0; reg < 4; ++reg) {
      float x2r = x2g[bRow0 + mbase + reg];
      float ps = 0.0f;
      #pragma unroll
      for (int ni = 0; ni < 4; ++ni) {
        float c = acc[mi][ni][reg];
        ps += __expf(__builtin_fmaf(-0.5f, x2r + s2v[ni], c)) * wv[ni];
      }
      ps += __shfl_xor(ps, 1);
      ps += __shfl_xor(ps, 2);
      ps += __shfl_xor(ps, 4);
      ps += __shfl_xor(ps, 8);
      if (l16 == 0) atomicAdd(&accOut[bRow0 + mbase + reg], ps);
    }
  }
}

// ============================================================

__global__ __launch_bounds__(256) void svm_finalize(
    const float* __restrict__ ws, const float* __restrict__ bias,
    float* __restrict__ out) {
  int i = blockIdx.x * 256 + threadIdx.x;
  if (i < BQ) out[i] = tanhf(ws[i] + bias[0]);  // acc at offset 0 in both layouts
}

extern "C" void kernel_launch(void* const* d_in, const int* in_sizes, int n_in,
                              void* d_out, int out_size, void* d_ws, size_t ws_size,
                              hipStream_t stream) {
  const float* x       = (const float*)d_in[0];  // [2048, 256]
  const float* s       = (const float*)d_in[1];  // [50000, 256]
  const float* labels  = (const float*)d_in[2];  // [50000]
  const float* lambdas = (const float*)d_in[3];  // [50000]
  const float* bias    = (const float*)d_in[4];  // [1]
  float* out = (float*)d_out;                    // [2048]
  float* ws  = (float*)d_ws;

  hipMemsetAsync(ws, 0, BQ * sizeof(float), stream);

  if (ws_size >= WS_TOTAL_BYTES) {
    svm_precvt<<<(NPAD + BQ + 3) / 4, 256, 0, stream>>>(x, s, labels, lambdas, ws);
    svm_main2<<<NCHUNKS * (BQ / TILE), 256, 0, stream>>>(ws);
  } else {
    svm_precompute<<<(NPTS + BQ + 3) / 4, 256, 0, stream>>>(x, s, labels, lambdas, ws);
    dim3 grid(NCHUNKS, BQ / TILE);
    svm_main<<<grid, 256, 0, stream>>>(x, s, ws);
  }
  svm_finalize<<<BQ / 256, 256, 0, stream>>>(ws, bias, out);
}

// Round 3
// 211.305 us; speedup vs baseline: 2.6417x; 1.1933x over previous
//
#include <hip/hip_runtime.h>
#include <hip/hip_bf16.h>

// Problem constants (fixed by the reference)
#define NPTS 50000   // N data points
#define DIM  256     // feature dim (K of the GEMM)
#define BQ   2048    // batch of queries (M of the GEMM)
#define NPAD 50048   // N padded to multiple of 128

#define TILE 128
#define BK   32
#define NCHUNKS 391  // NPAD/128
#define NGROUPS 32   // n-chunk groups (grid = 16 m-tiles x 32 groups)
#define LOG2E 1.4426950408889634f

// ---------- fast-path ws layout (float offsets) ----------
//  acc   [0,      2048)
//  x2h   [2048,   4096)   0.5*log2e*||x||^2
//  s2h   [4096,  54144)   0.5*log2e*||s||^2 (NPAD)
//  w     [54144, 104192)  labels*relu(lambdas) (NPAD, 0-padded)
//  xb    [104192, 366336)   bf16 x
//  sb    [366336, 6772480)  bf16 s (NPAD rows, 0-padded)
#define WS_ACC 0
#define WS_X2  2048
#define WS_S2  4096
#define WS_W   54144
#define WS_XB  104192
#define WS_SB  366336
#define WS_TOTAL_BYTES (6772480ull * 4ull)  // 27,089,920 B

// ---------- v1 fallback ws layout ----------
#define V1_ACC 0
#define V1_X2  2048
#define V1_S2  4096
#define V1_W   54096

typedef __bf16 bf16x8 __attribute__((ext_vector_type(8)));
typedef __bf16 bf16x4 __attribute__((ext_vector_type(4)));
typedef float  f32x4  __attribute__((ext_vector_type(4)));
typedef unsigned int u32;

__device__ __forceinline__ void async_copy16(const __bf16* g, __bf16* l) {
  __builtin_amdgcn_global_load_lds(
      (const __attribute__((address_space(1))) u32*)g,
      (__attribute__((address_space(3))) u32*)l, 16, 0, 0);
}

// ============================================================
// FAST PATH
// ============================================================

// 4 rows per wave: fp32->bf16 convert into ws, plus scaled norms and w.
__global__ __launch_bounds__(256) void svm_precvt(
    const float* __restrict__ x, const float* __restrict__ s,
    const float* __restrict__ labels, const float* __restrict__ lambdas,
    float* __restrict__ ws) {
  int grp  = blockIdx.x * 4 + (threadIdx.x >> 6);
  int lane = threadIdx.x & 63;
  __bf16* xb = (__bf16*)(ws + WS_XB);
  __bf16* sb = (__bf16*)(ws + WS_SB);

  #pragma unroll
  for (int j = 0; j < 4; ++j) {
    int wid = grp * 4 + j;
    if (wid < NPAD) {
      float4 v = make_float4(0.f, 0.f, 0.f, 0.f);
      if (wid < NPTS)
        v = reinterpret_cast<const float4*>(s + (size_t)wid * DIM)[lane];
      bf16x4 h = { (__bf16)v.x, (__bf16)v.y, (__bf16)v.z, (__bf16)v.w };
      *reinterpret_cast<bf16x4*>(sb + (size_t)wid * DIM + lane * 4) = h;
      float ss = v.x * v.x + v.y * v.y + v.z * v.z + v.w * v.w;
      #pragma unroll
      for (int off = 32; off > 0; off >>= 1) ss += __shfl_xor(ss, off);
      if (lane == 0) {
        ws[WS_S2 + wid] = 0.5f * LOG2E * ss;
        float lam = (wid < NPTS) ? lambdas[wid] : 0.0f;
        float lab = (wid < NPTS) ? labels[wid] : 0.0f;
        ws[WS_W + wid] = lab * (lam > 0.0f ? lam : 0.0f);
      }
    } else if (wid < NPAD + BQ) {
      int r = wid - NPAD;
      float4 v = reinterpret_cast<const float4*>(x + (size_t)r * DIM)[lane];
      bf16x4 h = { (__bf16)v.x, (__bf16)v.y, (__bf16)v.z, (__bf16)v.w };
      *reinterpret_cast<bf16x4*>(xb + (size_t)r * DIM + lane * 4) = h;
      float ss = v.x * v.x + v.y * v.y + v.z * v.z + v.w * v.w;
      #pragma unroll
      for (int off = 32; off > 0; off >>= 1) ss += __shfl_xor(ss, off);
      if (lane == 0) ws[WS_X2 + r] = 0.5f * LOG2E * ss;
    }
  }
}

// Block = 128-row m-stripe, loops over ~12 n-chunks of 128.
// A fragments pinned in registers; LDS holds only the current B chunk.
__global__ __launch_bounds__(256, 2) void svm_main3(float* __restrict__ ws) {
  __shared__ __bf16 sB[8 * 128 * 32];  // [kt][n][32k], 64 KB

  const __bf16* xb = (const __bf16*)(ws + WS_XB);
  const __bf16* sb = (const __bf16*)(ws + WS_SB);
  const float* x2g = ws + WS_X2;
  const float* s2g = ws + WS_S2;
  const float* wg  = ws + WS_W;
  float* accOut    = ws + WS_ACC;

  const int t    = threadIdx.x;
  const int wave = t >> 6;
  const int lane = t & 63;
  const int quad = lane >> 4;
  const int l16  = lane & 15;
  const int bid  = blockIdx.x;
  const int g    = bid & 31;        // n-group: all 16 m-blocks of g share an XCD
  const int mt   = bid >> 5;        // m-tile 0..15
  const int m0   = mt * TILE;
  const int c0   = g * 12 + (g < 7 ? g : 7);
  const int cnt  = 12 + (g < 7 ? 1 : 0);

  // A fragments for this wave's 32 m-rows, all of K. 64 VGPRs, loaded once.
  bf16x8 af[2][8];
  #pragma unroll
  for (int mi = 0; mi < 2; ++mi)
    #pragma unroll
    for (int kt = 0; kt < 8; ++kt)
      af[mi][kt] = *reinterpret_cast<const bf16x8*>(
          xb + (size_t)(m0 + wave * 32 + mi * 16 + l16) * DIM + kt * BK + quad * 8);

  // per-lane output rows (C layout: row = quad*4 + reg)
  float x2r[2][4];
  #pragma unroll
  for (int mi = 0; mi < 2; ++mi)
    #pragma unroll
    for (int r = 0; r < 4; ++r)
      x2r[mi][r] = x2g[m0 + wave * 32 + mi * 16 + quad * 4 + r];

  float runAcc[2][4] = {{0.f, 0.f, 0.f, 0.f}, {0.f, 0.f, 0.f, 0.f}};

  for (int c = c0; c < c0 + cnt; ++c) {
    __syncthreads();  // prior chunk's LDS reads done
    // Stage B chunk: [kt][n][32k]; each instr writes 1 KB (lane*16B contiguous).
    #pragma unroll
    for (int i = 0; i < 16; ++i) {
      int chunk = wave * 16 + i;           // 0..63
      int kt = chunk >> 3;
      int nb = (chunk & 7) * 16;
      const __bf16* src = sb + (size_t)(c * TILE + nb + (lane >> 2)) * DIM
                             + kt * BK + (lane & 3) * 8;
      async_copy16(src, &sB[kt * 4096 + nb * BK] + lane * 8);
    }
    __syncthreads();  // vmcnt drain

    // issue epilogue operands early (consumed after the kt loop)
    float s2t[8], wvv[8];
    #pragma unroll
    for (int ni = 0; ni < 8; ++ni) {
      int n = c * TILE + ni * 16 + l16;
      s2t[ni] = s2g[n];
      wvv[ni] = wg[n];
    }

    f32x4 acc[2][8];
    #pragma unroll
    for (int mi = 0; mi < 2; ++mi)
      #pragma unroll
      for (int ni = 0; ni < 8; ++ni)
        acc[mi][ni] = (f32x4)(0.0f);

    #pragma unroll 2
    for (int kt = 0; kt < 8; ++kt) {
      bf16x8 bfv[8];
      #pragma unroll
      for (int ni = 0; ni < 8; ++ni)
        bfv[ni] = *reinterpret_cast<const bf16x8*>(
            &sB[kt * 4096 + (ni * 16 + l16) * BK + quad * 8]);
      #pragma unroll
      for (int mi = 0; mi < 2; ++mi)
        #pragma unroll
        for (int ni = 0; ni < 8; ++ni)
          acc[mi][ni] = __builtin_amdgcn_mfma_f32_16x16x32_bf16(
              af[mi][kt], bfv[ni], acc[mi][ni], 0, 0, 0);
    }

    // Epilogue: K*w = exp2(c*log2e - x2h - s2h) * w, accumulate in registers.
    #pragma unroll
    for (int mi = 0; mi < 2; ++mi)
      #pragma unroll
      for (int reg = 0; reg < 4; ++reg) {
        float xh = x2r[mi][reg];
        float p = 0.0f;
        #pragma unroll
        for (int ni = 0; ni < 8; ++ni)
          p += exp2f(__builtin_fmaf(acc[mi][ni][reg], LOG2E, -(xh + s2t[ni]))) * wvv[ni];
        runAcc[mi][reg] += p;
      }
  }

  // one reduction + atomic per output row per block
  #pragma unroll
  for (int mi = 0; mi < 2; ++mi)
    #pragma unroll
    for (int reg = 0; reg < 4; ++reg) {
      float v = runAcc[mi][reg];
      v += __shfl_xor(v, 1);
      v += __shfl_xor(v, 2);
      v += __shfl_xor(v, 4);
      v += __shfl_xor(v, 8);
      if (l16 == 0)
        atomicAdd(&accOut[m0 + wave * 32 + mi * 16 + quad * 4 + reg], v);
    }
}

// ============================================================
// V1 FALLBACK (used only if ws_size too small)
// ============================================================

__global__ __launch_bounds__(256) void svm_precompute(
    const float* __restrict__ x, const float* __restrict__ s,
    const float* __restrict__ labels, const float* __restrict__ lambdas,
    float* __restrict__ ws) {
  int wid  = blockIdx.x * 4 + (threadIdx.x >> 6);
  int lane = threadIdx.x & 63;
  const float* src;
  if (wid < NPTS)           src = s + (size_t)wid * DIM;
  else if (wid < NPTS + BQ) src = x + (size_t)(wid - NPTS) * DIM;
  else return;
  float4 v = reinterpret_cast<const float4*>(src)[lane];
  float ss = v.x * v.x + v.y * v.y + v.z * v.z + v.w * v.w;
  #pragma unroll
  for (int off = 32; off > 0; off >>= 1) ss += __shfl_xor(ss, off);
  if (lane == 0) {
    if (wid < NPTS) {
      ws[V1_S2 + wid] = ss;
      float lam = lambdas[wid];
      ws[V1_W + wid] = labels[wid] * (lam > 0.0f ? lam : 0.0f);
    } else {
      ws[V1_X2 + (wid - NPTS)] = ss;
    }
  }
}

__global__ __launch_bounds__(256) void svm_main(
    const float* __restrict__ x, const float* __restrict__ s,
    const float* __restrict__ ws) {
  __shared__ __bf16 sA[TILE * BK];
  __shared__ __bf16 sB[TILE * BK];

  const int t    = threadIdx.x;
  const int wave = t >> 6;
  const int lane = t & 63;
  const int quad = lane >> 4;
  const int l16  = lane & 15;
  const int wm   = (wave & 1) * 64;
  const int wn   = (wave >> 1) * 64;
  const int bRow0 = blockIdx.y * TILE;
  const int n0    = blockIdx.x * TILE;

  f32x4 acc[4][4];
  #pragma unroll
  for (int i = 0; i < 4; ++i)
    #pragma unroll
    for (int j = 0; j < 4; ++j)
      acc[i][j] = (f32x4)(0.0f);

  for (int kt = 0; kt < DIM / BK; ++kt) {
    const int k0 = kt * BK;
    __syncthreads();
    #pragma unroll
    for (int i = 0; i < 4; ++i) {
      int slot = t + i * 256;
      int r  = slot >> 3;
      int c4 = slot & 7;
      float4 va = reinterpret_cast<const float4*>(
          x + (size_t)(bRow0 + r) * DIM + k0)[c4];
      bf16x4 ha = { (__bf16)va.x, (__bf16)va.y, (__bf16)va.z, (__bf16)va.w };
      *reinterpret_cast<bf16x4*>(&sA[r * BK + c4 * 4]) = ha;

      int nrow = n0 + r;
      float4 vb = make_float4(0.f, 0.f, 0.f, 0.f);
      if (nrow < NPTS)
        vb = reinterpret_cast<const float4*>(
            s + (size_t)nrow * DIM + k0)[c4];
      bf16x4 hb = { (__bf16)vb.x, (__bf16)vb.y, (__bf16)vb.z, (__bf16)vb.w };
      *reinterpret_cast<bf16x4*>(&sB[r * BK + c4 * 4]) = hb;
    }
    __syncthreads();

    bf16x8 af[4], bfv[4];
    #pragma unroll
    for (int mi = 0; mi < 4; ++mi)
      af[mi] = *reinterpret_cast<const bf16x8*>(
          &sA[(wm + mi * 16 + l16) * BK + quad * 8]);
    #pragma unroll
    for (int ni = 0; ni < 4; ++ni)
      bfv[ni] = *reinterpret_cast<const bf16x8*>(
          &sB[(wn + ni * 16 + l16) * BK + quad * 8]);
    #pragma unroll
    for (int mi = 0; mi < 4; ++mi)
      #pragma unroll
      for (int ni = 0; ni < 4; ++ni)
        acc[mi][ni] = __builtin_amdgcn_mfma_f32_16x16x32_bf16(
            af[mi], bfv[ni], acc[mi][ni], 0, 0, 0);
  }

  const float* x2g = ws + V1_X2;
  const float* s2g = ws + V1_S2;
  const float* wg  = ws + V1_W;
  float* accOut    = (float*)ws + V1_ACC;

  float s2v[4], wv[4];
  #pragma unroll
  for (int ni = 0; ni < 4; ++ni) {
    int n = n0 + wn + ni * 16 + l16;
    bool ok = n < NPTS;
    s2v[ni] = ok ? s2g[n] : 0.0f;
    wv[ni]  = ok ? wg[n]  : 0.0f;
  }
  #pragma unroll
  for (int mi = 0; mi < 4; ++mi) {
    const int mbase = wm + mi * 16 + quad * 4;
    #pragma unroll
    for (int reg = 0; reg < 4; ++reg) {
      float x2r = x2g[bRow0 + mbase + reg];
      float ps = 0.0f;
      #pragma unroll
      for (int ni = 0; ni < 4; ++ni) {
        float cc = acc[mi][ni][reg];
        ps += __expf(__builtin_fmaf(-0.5f, x2r + s2v[ni], cc)) * wv[ni];
      }
      ps += __shfl_xor(ps, 1);
      ps += __shfl_xor(ps, 2);
      ps += __shfl_xor(ps, 4);
      ps += __shfl_xor(ps, 8);
      if (l16 == 0) atomicAdd(&accOut[bRow0 + mbase + reg], ps);
    }
  }
}

// ============================================================

__global__ __launch_bounds__(256) void svm_finalize(
    const float* __restrict__ ws, const float* __restrict__ bias,
    float* __restrict__ out) {
  int i = blockIdx.x * 256 + threadIdx.x;
  if (i < BQ) out[i] = tanhf(ws[i] + bias[0]);  // acc at offset 0 in both layouts
}

extern "C" void kernel_launch(void* const* d_in, const int* in_sizes, int n_in,
                              void* d_out, int out_size, void* d_ws, size_t ws_size,
                              hipStream_t stream) {
  const float* x       = (const float*)d_in[0];  // [2048, 256]
  const float* s       = (const float*)d_in[1];  // [50000, 256]
  const float* labels  = (const float*)d_in[2];  // [50000]
  const float* lambdas = (const float*)d_in[3];  // [50000]
  const float* bias    = (const float*)d_in[4];  // [1]
  float* out = (float*)d_out;                    // [2048]
  float* ws  = (float*)d_ws;

  hipMemsetAsync(ws, 0, BQ * sizeof(float), stream);

  if (ws_size >= WS_TOTAL_BYTES) {
    // 4 rows per wave, 16 rows per block
    svm_precvt<<<(NPAD + BQ + 15) / 16, 256, 0, stream>>>(x, s, labels, lambdas, ws);
    svm_main3<<<16 * NGROUPS, 256, 0, stream>>>(ws);
  } else {
    svm_precompute<<<(NPTS + BQ + 3) / 4, 256, 0, stream>>>(x, s, labels, lambdas, ws);
    dim3 grid(NCHUNKS, BQ / TILE);
    svm_main<<<grid, 256, 0, stream>>>(x, s, ws);
  }
  svm_finalize<<<BQ / 256, 256, 0, stream>>>(ws, bias, out);
}